// Round 9
// baseline (369.524 us; speedup 1.0000x reference)
//
#include <hip/hip_runtime.h>

#define D 128
#define NLVL 17          // parent levels 0..16
#define TS 128           // rows per big GEMM tile
#define LVLPAD 1024      // per-level perm slack for group padding
#define LDSTR 136        // LDS row stride in bf16 elems (272B: conflict-free b128)
#define LEAF_BLKS 1032   // ceil((131072 + 8*127)/128)
#define CHUNK 2048
#define CNT_BLKS 128

typedef float  floatx4 __attribute__((ext_vector_type(4)));
typedef short  shortx8 __attribute__((ext_vector_type(8)));

__device__ __forceinline__ unsigned short f2bf(float f) {   // RNE fp32->bf16
    unsigned u = __float_as_uint(f);
    u += 0x7FFFu + ((u >> 16) & 1u);
    return (unsigned short)(u >> 16);
}
__device__ __forceinline__ float bf2f(unsigned short h) {
    return __uint_as_float(((unsigned)h) << 16);
}
__device__ __forceinline__ int lvl_base_dev(int l) { return ((2 << l) - 2) + LVLPAD * l; }

// ============ prep (fused): compose->cwt+dcomp | ewt/dwt transpose | sv/s0+ctr0 | count | vec2bf ============
__global__ __launch_bounds__(256) void prep_kernel(
    const float* __restrict__ dW, const float* __restrict__ db,
    const float* __restrict__ eW, const float* __restrict__ eb,
    const float* __restrict__ sWs, const float* __restrict__ vecs,
    const int* __restrict__ edges,
    unsigned short* __restrict__ ewt, unsigned short* __restrict__ cwt,
    unsigned short* __restrict__ dwt, float* __restrict__ dcomp,
    float* __restrict__ sv, float* __restrict__ s0, int* __restrict__ ctr,
    int* __restrict__ gcnt128, int Nn,
    unsigned short* __restrict__ vbf, int n4)
{
    __shared__ float smem[8448];
    const int b = blockIdx.x, t = threadIdx.x;
    if (b < 32) {
        // ---- compose: C_e[:, cc*32..] = dW @ eW_e -> cwt (bf16 [n][k]) + dcomp ----
        float* w_s = smem;          // [k][32] slice of eW_e
        float* cs  = smem + 4096;   // [k][33] C block (padded)
        const int e = b >> 2, cc = b & 3;
        for (int i = t; i < D * 8; i += 256) {
            const int k = i >> 3, j4 = i & 7;
            ((float4*)w_s)[i] = ((const float4*)eW)[((size_t)e * D + k) * 32 + cc * 8 + j4];
        }
        __syncthreads();
        const int r2 = t >> 1, h = t & 1;
        float4 acc[4];
        #pragma unroll
        for (int m = 0; m < 4; m++) acc[m] = make_float4(0.f, 0.f, 0.f, 0.f);
        for (int k = 0; k < D; k++) {
            const float a = dW[(size_t)r2 * D + k];
            #pragma unroll
            for (int m = 0; m < 4; m++) {
                const float4 w4 = ((const float4*)w_s)[k * 8 + h * 4 + m];
                acc[m].x += a * w4.x; acc[m].y += a * w4.y; acc[m].z += a * w4.z; acc[m].w += a * w4.w;
            }
        }
        #pragma unroll
        for (int m = 0; m < 4; m++) {
            cs[r2 * 33 + h * 16 + m * 4 + 0] = acc[m].x;
            cs[r2 * 33 + h * 16 + m * 4 + 1] = acc[m].y;
            cs[r2 * 33 + h * 16 + m * 4 + 2] = acc[m].z;
            cs[r2 * 33 + h * 16 + m * 4 + 3] = acc[m].w;
        }
        __syncthreads();
        {
            const int nn = t >> 3, kseg = t & 7, k0 = kseg * 16;
            unsigned ow[8];
            #pragma unroll
            for (int i2 = 0; i2 < 8; i2++) {
                const unsigned short lo = f2bf(cs[(k0 + 2 * i2) * 33 + nn]);
                const unsigned short hi = f2bf(cs[(k0 + 2 * i2 + 1) * 33 + nn]);
                ow[i2] = (unsigned)lo | ((unsigned)hi << 16);
            }
            uint4* dstp = (uint4*)(cwt + (size_t)e * D * D + (size_t)(cc * 32 + nn) * D + k0);
            dstp[0] = make_uint4(ow[0], ow[1], ow[2], ow[3]);
            dstp[1] = make_uint4(ow[4], ow[5], ow[6], ow[7]);
        }
        if (t < 32) {
            float a2 = 0.f;
            for (int k = 0; k < D; k++) a2 += db[k] * w_s[k * 32 + t];
            dcomp[e * D + cc * 32 + t] = a2 + eb[e * D + cc * 32 + t];
        }
    } else if (b < 41) {
        // ---- transpose to bf16 [n][k]: b-32<8 -> ewt[e], b==40 -> dwt ----
        float* lds = smem;   // 64 x 129
        const int bb = b - 32;
        const float* src = (bb < 8) ? (eW + (size_t)bb * D * D) : dW;
        unsigned short* dst = (bb < 8) ? (ewt + (size_t)bb * D * D) : dwt;
        for (int half = 0; half < 2; half++) {
            __syncthreads();
            for (int i = t; i < 64 * D / 4; i += 256) {
                float4 v = ((const float4*)src)[half * (64 * D / 4) + i];
                const int k = (i * 4) >> 7, n = (i * 4) & 127;
                lds[k * 129 + n]     = v.x;
                lds[k * 129 + n + 1] = v.y;
                lds[k * 129 + n + 2] = v.z;
                lds[k * 129 + n + 3] = v.w;
            }
            __syncthreads();
            const int n = t >> 1, hh = t & 1;
            for (int kk = 0; kk < 32; kk++) {
                const int k = hh * 32 + kk;
                dst[(size_t)n * D + half * 64 + k] = f2bf(lds[k * 129 + n]);
            }
        }
    } else if (b == 41) {
        // ---- sv = data_W @ score_W, s0 = data_b . score_W; zero ctr ----
        float* red = smem;
        if (t < 32) ctr[t] = 0;
        if (t < D) {
            float acc = 0.f;
            for (int j = 0; j < D; j++) acc += dW[(size_t)t * D + j] * sWs[j];
            sv[t] = acc;
        }
        red[t] = (t < D) ? db[t] * sWs[t] : 0.f;
        __syncthreads();
        for (int s = 128; s > 0; s >>= 1) { if (t < s) red[t] += red[t + s]; __syncthreads(); }
        if (t == 0) s0[0] = red[0];
    } else if (b < 42 + CNT_BLKS) {
        // ---- counts for parent-levels 13..16 (children c >= 16383) ----
        int* lc = (int*)smem;
        if (t < 32) lc[t] = 0;
        __syncthreads();
        for (int c = 16383 + (b - 42) * 256 + t; c < Nn; c += CNT_BLKS * 256) {
            const int e = edges[c];
            const int p = (c - 1) >> 1;
            const int l = 31 - __clz(p + 1);      // 13..16
            atomicAdd(&lc[(l - 13) * 8 + e], 1);
        }
        __syncthreads();
        if (t < 32) gcnt128[(b - 42) * 32 + t] = lc[t];
    } else {
        // ---- vec2bf grid-stride ----
        for (int i = (b - 42 - CNT_BLKS) * 256 + t; i < n4; i += (gridDim.x - 42 - CNT_BLKS) * 256) {
            const float4 v = ((const float4*)vecs)[i];
            uint2 o;
            o.x = (unsigned)f2bf(v.x) | ((unsigned)f2bf(v.y) << 16);
            o.y = (unsigned)f2bf(v.z) | ((unsigned)f2bf(v.w) << 16);
            ((uint2*)vbf)[i] = o;
        }
    }
}

// ============ place (+local prefix): levels 13..16; block 0 publishes gstart/glim ============
__global__ __launch_bounds__(256) void place_kernel(
    const int* __restrict__ edges, const int* __restrict__ gcnt128,
    int* __restrict__ gstart, int* __restrict__ glim,
    int* __restrict__ ctr, int* __restrict__ perm, int Nn)
{
    __shared__ unsigned char key_s[CHUNK];
    __shared__ int part[256];
    __shared__ int tot[32];
    __shared__ int lcnt[32], lbase[32];
    __shared__ int gs_s[4 * 9], gl_s[32];
    const int t = threadIdx.x;
    {   // redundant per-block reduction of gcnt128 -> tot[32]
        const int k = t & 31, bs = t >> 5;
        int s = 0;
        for (int bb = bs; bb < CNT_BLKS; bb += 8) s += gcnt128[bb * 32 + k];
        part[t] = s;
    }
    if (t < 32) lcnt[t] = 0;
    __syncthreads();
    if (t < 32) {
        int tt = 0;
        #pragma unroll
        for (int i = 0; i < 8; i++) tt += part[t + 32 * i];
        tot[t] = tt;
    }
    __syncthreads();
    if (t == 0) {
        for (int li = 0; li < 4; li++) {
            int acc = 0;
            for (int e = 0; e < 8; e++) {
                gs_s[li * 9 + e] = acc;
                gl_s[li * 8 + e] = acc + tot[li * 8 + e];
                acc = (acc + tot[li * 8 + e] + (TS - 1)) & ~(TS - 1);
            }
            gs_s[li * 9 + 8] = acc;
        }
    }
    __syncthreads();
    if (blockIdx.x == 0 && t < 36) {
        gstart[13 * 9 + t] = gs_s[t];
        if (t < 32) glim[13 * 8 + t] = gl_s[t];
    }
    const int base = 16383 + blockIdx.x * CHUNK;
    for (int i = t; i < CHUNK; i += 256) {
        const int c = base + i;
        if (c < Nn) {
            const int e = edges[c];
            const int p = (c - 1) >> 1;
            const int l = 31 - __clz(p + 1);
            const int kk = (l - 13) * 8 + e;
            key_s[i] = (unsigned char)kk;
            atomicAdd(&lcnt[kk], 1);
        } else key_s[i] = 255;
    }
    __syncthreads();
    if (t < 32) {
        const int n = lcnt[t];
        lbase[t] = n ? atomicAdd(&ctr[t], n) : 0;
        lcnt[t] = 0;
    }
    __syncthreads();
    for (int i = t; i < CHUNK; i += 256) {
        const int c = base + i;
        if (c >= Nn) continue;
        const int kk = key_s[i];
        if (kk == 255) continue;
        const int off = atomicAdd(&lcnt[kk], 1);
        const int l = (kk >> 3) + 13, e = kk & 7;
        const int pos = gs_s[(l - 13) * 9 + e] + lbase[kk] + off;
        perm[lvl_base_dev(l) + pos] = c;
    }
}

// ============ merged leaf GEMM + embed: barrier-free, A gathered direct into MFMA frags ============
// Wave owns 32 rows (2 m-tiles x 16). A-frag [m=lane&15][k=(lane>>4)*8+ks*32] loaded straight
// from vbf[data[c]]; B direct from L2-hot W[n][k]; epilogue via per-wave LDS slice.
__global__ __launch_bounds__(256, 4) void leaf_embed_kernel(
    unsigned short* __restrict__ X,
    const unsigned short* __restrict__ vbf,
    const int* __restrict__ data,
    const int* __restrict__ perm,
    const int* __restrict__ gstart9,
    const int* __restrict__ glim8,
    const unsigned short* __restrict__ cwt,
    const float* __restrict__ dcomp,
    const float* __restrict__ sv, const float* __restrict__ s0p,
    const unsigned short* __restrict__ dwt,
    const float* __restrict__ db,
    float* __restrict__ out,
    int NI, int lbase_leaf)
{
    __shared__ unsigned short y_s[4][32 * LDSTR];   // per-wave epilogue slices (~34.8 KB)
    __shared__ int crow[128];
    const int t = threadIdx.x;
    const int lane = t & 63, wv = t >> 6;
    const int cq = lane & 15, q = lane >> 4;
    const bool is_leaf = (blockIdx.x < LEAF_BLKS);

    int e = 0, ts;
    const unsigned short* Wg;
    const float* bias;
    if (is_leaf) {
        ts = blockIdx.x * TS;
        if (ts >= gstart9[8]) return;
        #pragma unroll
        for (int j = 1; j < 8; j++) if (ts >= gstart9[j]) e = j;
        Wg = cwt + (size_t)e * D * D;
        bias = dcomp + (size_t)e * D;
    } else {
        ts = (blockIdx.x - LEAF_BLKS) * TS;
        Wg = dwt;
        bias = db;
    }

    int c[2];
    const unsigned short* arow[2];
    #pragma unroll
    for (int mti = 0; mti < 2; mti++) {
        const int rl = wv * 32 + mti * 16 + cq;
        int cc;
        if (is_leaf) {
            const int p = ts + rl;
            cc = (p < glim8[e]) ? perm[lbase_leaf + p] : -1;
        } else {
            const int node = ts + rl;
            cc = (node < NI) ? node : -1;
        }
        c[mti] = cc;
        arow[mti] = (cc >= 0) ? (vbf + (size_t)data[cc] * D) : (const unsigned short*)0;
        if (q == 0) crow[rl] = cc;
    }

    const floatx4 z4 = {0.f, 0.f, 0.f, 0.f};
    floatx4 acc[2][8];
    #pragma unroll
    for (int i = 0; i < 8; i++) { acc[0][i] = z4; acc[1][i] = z4; }
    float sc0 = 0.f, sc1 = 0.f;

    #pragma unroll
    for (int ks = 0; ks < 4; ks++) {
        shortx8 af[2];
        #pragma unroll
        for (int mti = 0; mti < 2; mti++) {
            if (c[mti] >= 0) af[mti] = *(const shortx8*)(arow[mti] + ks * 32 + q * 8);
            else { shortx8 z = {0,0,0,0,0,0,0,0}; af[mti] = z; }
        }
        if (is_leaf) {   // fused score partials (per-lane 8 elems of its row)
            #pragma unroll
            for (int j = 0; j < 8; j++) {
                const float svj = sv[ks * 32 + q * 8 + j];
                sc0 += bf2f((unsigned short)af[0][j]) * svj;
                sc1 += bf2f((unsigned short)af[1][j]) * svj;
            }
        }
        #pragma unroll
        for (int nt = 0; nt < 8; nt++) {
            const shortx8 bfr = *(const shortx8*)(Wg + (size_t)(nt * 16 + cq) * D + ks * 32 + q * 8);
            acc[0][nt] = __builtin_amdgcn_mfma_f32_16x16x32_bf16(af[0], bfr, acc[0][nt], 0, 0, 0);
            acc[1][nt] = __builtin_amdgcn_mfma_f32_16x16x32_bf16(af[1], bfr, acc[1][nt], 0, 0, 0);
        }
    }
    if (is_leaf) {   // reduce across the 4 q-lanes sharing each row (lanes m, m+16, m+32, m+48)
        sc0 += __shfl_xor(sc0, 16, 64); sc0 += __shfl_xor(sc0, 32, 64);
        sc1 += __shfl_xor(sc1, 16, 64); sc1 += __shfl_xor(sc1, 32, 64);
        if (q == 0) {
            if (c[0] >= 0) out[c[0]] = sc0 + s0p[0];
            if (c[1] >= 0) out[c[1]] = sc1 + s0p[0];
        }
    }
    // epilogue: bias + f2bf into per-wave LDS slice (rows = mti*16 + q*4 + rg, col = nt*16+cq)
    unsigned short* ys = y_s[wv];
    #pragma unroll
    for (int nt = 0; nt < 8; nt++) {
        const int n = nt * 16 + cq;
        const float bn = bias[n];
        #pragma unroll
        for (int mti = 0; mti < 2; mti++) {
            #pragma unroll
            for (int rg = 0; rg < 4; rg++)
                ys[(mti * 16 + q * 4 + rg) * LDSTR + n] = f2bf(acc[mti][nt][rg] + bn);
        }
    }
    // coalesced writeback: 2 lanes per row (wave-internal, no barrier needed)
    const int r2 = lane >> 1, h = lane & 1;
    const int cc = crow[wv * 32 + r2];
    if (cc >= 0) {
        uint4* dst = (uint4*)(X + (size_t)cc * D + h * 64);
        const uint4* srcl = (const uint4*)(ys + r2 * LDSTR + h * 64);
        #pragma unroll
        for (int j = 0; j < 8; j++) dst[j] = srcl[j];
    }
}

// ============ big tree GEMM (parent-levels 15..13): combine+score+ReLU staged, W direct ============
__global__ __launch_bounds__(256, 4) void tree_gemm_kernel(
    unsigned short* __restrict__ X,
    const int* __restrict__ perm,
    const int* __restrict__ gstart9,
    const int* __restrict__ glim8,
    const unsigned short* __restrict__ ewt,
    const float* __restrict__ eb,
    const float* __restrict__ svec,
    float* __restrict__ out,
    int lbase)
{
    __shared__ unsigned short a_s[TS * LDSTR];
    const int t = threadIdx.x;
    const int ts = blockIdx.x * TS;
    if (ts >= gstart9[8]) return;
    int e = 0;
    #pragma unroll
    for (int j = 1; j < 8; j++) if (ts >= gstart9[j]) e = j;
    const int r = t >> 1, h = t & 1;
    const int p = ts + r;
    const int c = (p < glim8[e]) ? perm[lbase + p] : -1;
    const unsigned short* Wg = ewt + (size_t)e * D * D;

    {   // stage A: fused combine + score + ReLU
        unsigned short* dst = a_s + r * LDSTR + h * 64;
        if (c >= 0) {
            const uint4* xr = (const uint4*)(X + (size_t)c * D + h * 64);
            const uint4* ya = (const uint4*)(X + (size_t)(2 * c + 1) * D + h * 64);
            const uint4* yb = (const uint4*)(X + (size_t)(2 * c + 2) * D + h * 64);
            const float inv3 = 1.0f / 3.0f;
            float sc = 0.f;
            #pragma unroll
            for (int j = 0; j < 8; j++) {
                uint4 ra = xr[j], rb = ya[j], rc = yb[j];
                const unsigned* pa = (const unsigned*)&ra;
                const unsigned* pb = (const unsigned*)&rb;
                const unsigned* pc = (const unsigned*)&rc;
                unsigned ou[4];
                #pragma unroll
                for (int u = 0; u < 4; u++) {
                    const float h0 = (bf2f((unsigned short)pa[u]) + bf2f((unsigned short)pb[u])
                                    + bf2f((unsigned short)pc[u])) * inv3;
                    const float h1 = (bf2f((unsigned short)(pa[u] >> 16)) + bf2f((unsigned short)(pb[u] >> 16))
                                    + bf2f((unsigned short)(pc[u] >> 16))) * inv3;
                    const int n = h * 64 + j * 8 + u * 2;
                    sc += h0 * svec[n] + h1 * svec[n + 1];
                    unsigned short q0 = f2bf(h0), q1 = f2bf(h1);
                    q0 = (q0 & 0x8000u) ? 0 : q0;
                    q1 = (q1 & 0x8000u) ? 0 : q1;
                    ou[u] = (unsigned)q0 | ((unsigned)q1 << 16);
                }
                ((uint4*)dst)[j] = make_uint4(ou[0], ou[1], ou[2], ou[3]);
            }
            sc += __shfl_xor(sc, 1, 64);
            if (h == 0) out[c] = sc;
        } else {
            #pragma unroll
            for (int j = 0; j < 8; j++) ((uint4*)dst)[j] = make_uint4(0u, 0u, 0u, 0u);
        }
    }
    __syncthreads();
    const int lane = t & 63, wv = t >> 6;
    const int cq = lane & 15, q = lane >> 4;
    const floatx4 z4 = {0.f, 0.f, 0.f, 0.f};
    floatx4 acc[8][2];
    #pragma unroll
    for (int i = 0; i < 8; i++) { acc[i][0] = z4; acc[i][1] = z4; }
    #pragma unroll
    for (int ks = 0; ks < 4; ks++) {
        shortx8 bfr[2];
        #pragma unroll
        for (int nl = 0; nl < 2; nl++) {
            const int n = (wv * 2 + nl) * 16 + cq;
            bfr[nl] = *(const shortx8*)(Wg + (size_t)n * D + ks * 32 + q * 8);
        }
        #pragma unroll
        for (int mt = 0; mt < 8; mt++) {
            const shortx8 af = *(const shortx8*)(a_s + (mt * 16 + cq) * LDSTR + ks * 32 + q * 8);
            acc[mt][0] = __builtin_amdgcn_mfma_f32_16x16x32_bf16(af, bfr[0], acc[mt][0], 0, 0, 0);
            acc[mt][1] = __builtin_amdgcn_mfma_f32_16x16x32_bf16(af, bfr[1], acc[mt][1], 0, 0, 0);
        }
    }
    __syncthreads();
    #pragma unroll
    for (int nl = 0; nl < 2; nl++) {
        const int n = (wv * 2 + nl) * 16 + cq;
        const float bn = eb[(size_t)e * D + n];
        #pragma unroll
        for (int mt = 0; mt < 8; mt++) {
            #pragma unroll
            for (int rg = 0; rg < 4; rg++) {
                const int m = mt * 16 + q * 4 + rg;
                a_s[m * LDSTR + n] = f2bf(acc[mt][nl][rg] + bn);
            }
        }
    }
    __syncthreads();
    if (c >= 0) {
        uint4* dst = (uint4*)(X + (size_t)c * D + h * 64);
        const uint4* srcl = (const uint4*)(a_s + r * LDSTR + h * 64);
        #pragma unroll
        for (int j = 0; j < 8; j++) dst[j] = srcl[j];
    }
}

// ============ subtree kernel (top levels): bf16 W row-dot, __syncthreads between depths ============
__global__ __launch_bounds__(256) void sub_kernel(
    unsigned short* __restrict__ X,
    const unsigned short* __restrict__ ewt,   // bf16 [8][n][k]
    const float* __restrict__ eb,
    const int* __restrict__ edges,
    const float* __restrict__ sW,
    float* __restrict__ out,
    int rbase, int nlev)
{
    __shared__ __align__(16) float xbuf[4][D];
    const int t = threadIdx.x, wv = t >> 6, lane = t & 63;
    const int u = rbase + blockIdx.x;
    const int j2 = lane * 2;
    const float inv3 = 1.0f / 3.0f;

    for (int lev = nlev - 1; lev >= 0; lev--) {
        const int first = ((u + 1) << lev) - 1;
        const int cnt = 1 << lev;
        for (int i = wv; i < cnt; i += 4) {
            const int n = first + i;
            const unsigned ra = *(const unsigned*)(X + (size_t)n * D + j2);
            const unsigned rb = *(const unsigned*)(X + (size_t)(2 * n + 1) * D + j2);
            const unsigned rc = *(const unsigned*)(X + (size_t)(2 * n + 2) * D + j2);
            const float h0 = (bf2f((unsigned short)ra) + bf2f((unsigned short)rb)
                            + bf2f((unsigned short)rc)) * inv3;
            const float h1 = (bf2f((unsigned short)(ra >> 16)) + bf2f((unsigned short)(rb >> 16))
                            + bf2f((unsigned short)(rc >> 16))) * inv3;
            float sc = h0 * sW[j2] + h1 * sW[j2 + 1];
            #pragma unroll
            for (int o = 32; o > 0; o >>= 1) sc += __shfl_xor(sc, o, 64);
            if (lane == 0) out[n] = sc;
            if (n == 0) continue;
            float2 x2 = make_float2(fmaxf(h0, 0.f), fmaxf(h1, 0.f));
            *(float2*)(xbuf[wv] + j2) = x2;
            const int e = edges[n];
            // y[j2], y[j2+1] = dot(x, ewt[e][j2][:]), dot(x, ewt[e][j2+1][:])
            const unsigned short* W0 = ewt + (size_t)e * D * D + (size_t)j2 * D;
            float y0 = 0.f, y1 = 0.f;
            #pragma unroll 4
            for (int k8 = 0; k8 < 16; k8++) {
                const uint4 wa = *(const uint4*)(W0 + k8 * 8);
                const uint4 wb = *(const uint4*)(W0 + D + k8 * 8);
                const float4 xa = *(const float4*)(xbuf[wv] + k8 * 8);
                const float4 xb = *(const float4*)(xbuf[wv] + k8 * 8 + 4);
                y0 += bf2f((unsigned short)wa.x) * xa.x + bf2f((unsigned short)(wa.x >> 16)) * xa.y
                    + bf2f((unsigned short)wa.y) * xa.z + bf2f((unsigned short)(wa.y >> 16)) * xa.w
                    + bf2f((unsigned short)wa.z) * xb.x + bf2f((unsigned short)(wa.z >> 16)) * xb.y
                    + bf2f((unsigned short)wa.w) * xb.z + bf2f((unsigned short)(wa.w >> 16)) * xb.w;
                y1 += bf2f((unsigned short)wb.x) * xa.x + bf2f((unsigned short)(wb.x >> 16)) * xa.y
                    + bf2f((unsigned short)wb.y) * xa.z + bf2f((unsigned short)(wb.y >> 16)) * xa.w
                    + bf2f((unsigned short)wb.z) * xb.x + bf2f((unsigned short)(wb.z >> 16)) * xb.y
                    + bf2f((unsigned short)wb.w) * xb.z + bf2f((unsigned short)(wb.w >> 16)) * xb.w;
            }
            y0 += eb[e * D + j2];
            y1 += eb[e * D + j2 + 1];
            const unsigned o = (unsigned)f2bf(y0) | ((unsigned)f2bf(y1) << 16);
            *(unsigned*)(X + (size_t)n * D + j2) = o;
        }
        __syncthreads();
    }
}

extern "C" void kernel_launch(void* const* d_in, const int* in_sizes, int n_in,
                              void* d_out, int out_size, void* d_ws, size_t ws_size,
                              hipStream_t stream) {
    const int*   data      = (const int*)d_in[0];
    const int*   edges     = (const int*)d_in[1];
    const float* data_vecs = (const float*)d_in[2];
    const float* data_W    = (const float*)d_in[3];
    const float* data_b    = (const float*)d_in[4];
    const float* edge_W    = (const float*)d_in[5];
    const float* edge_b    = (const float*)d_in[6];
    const float* score_W   = (const float*)d_in[7];
    float* out = (float*)d_out;

    const int Nn = in_sizes[0];          // 2^18 - 1
    const int NI = Nn >> 1;              // internal nodes: 2^17 - 1
    const int VD = in_sizes[2];          // V * D
    const int PERM_TOTAL = (Nn - 1) + LVLPAD * NLVL;

    char* w = (char*)d_ws;
    size_t off = 0;
    unsigned short* X = (unsigned short*)(w + off); off += (size_t)Nn * D * 2;
    int* perm = (int*)(w + off);  off += (size_t)PERM_TOTAL * 4;
    off = (off + 255) & ~(size_t)255;
    int* gstart  = (int*)(w + off); off += NLVL * 9 * 4;
    int* glim    = (int*)(w + off); off += NLVL * 8 * 4;
    int* gcnt128 = (int*)(w + off); off += CNT_BLKS * 32 * 4;
    int* ctr     = (int*)(w + off); off += 32 * 4;
    off = (off + 255) & ~(size_t)255;
    float* dcomp = (float*)(w + off); off += 8 * D * 4;
    float* sv    = (float*)(w + off); off += D * 4;
    float* s0    = (float*)(w + off); off += 256;
    off = (off + 255) & ~(size_t)255;
    unsigned short* ewt = (unsigned short*)(w + off); off += (size_t)8 * D * D * 2;
    unsigned short* cwt = (unsigned short*)(w + off); off += (size_t)8 * D * D * 2;
    unsigned short* dwt = (unsigned short*)(w + off); off += (size_t)D * D * 2;
    off = (off + 255) & ~(size_t)255;
    unsigned short* vbf = (unsigned short*)(w + off); off += (size_t)VD * 2;

    // 1: fused prep (weights, sv/s0, ctr zero, counts, vec2bf)
    prep_kernel<<<42 + CNT_BLKS + 1024, 256, 0, stream>>>(
        data_W, data_b, edge_W, edge_b, score_W, data_vecs, edges,
        ewt, cwt, dwt, dcomp, sv, s0, ctr, gcnt128, Nn, vbf, VD / 4);

    // 2: place (+redundant local prefix; block 0 publishes gstart/glim)
    const int place_blks = (Nn - 16383 + CHUNK - 1) / CHUNK;
    place_kernel<<<place_blks, 256, 0, stream>>>(edges, gcnt128, gstart, glim, ctr, perm, Nn);

    // 3: merged leaf GEMM (node-level 17) + embed (internal raw), barrier-free
    {
        const int embed_blks = (NI + TS - 1) / TS;
        const int lbase_leaf = ((2 << 16) - 2) + LVLPAD * 16;
        leaf_embed_kernel<<<LEAF_BLKS + embed_blks, 256, 0, stream>>>(
            X, vbf, data, perm, gstart + 16 * 9, glim + 16 * 8,
            cwt, dcomp, sv, s0, dwt, data_b, out, NI, lbase_leaf);
    }

    // 4..6: big internal parent-levels 15..13 (node-levels 16..14)
    for (int l = 15; l >= 13; l--) {
        const int M = 2 << l;
        const int lbase = ((2 << l) - 2) + LVLPAD * l;
        tree_gemm_kernel<<<M / TS + 8, 256, 0, stream>>>(
            X, perm, gstart + l * 9, glim + l * 8, ewt, edge_b, score_W, out, lbase);
    }

    // 7..10: top of tree via subtree-owned blocks (bf16 W)
    sub_kernel<<<2048, 256, 0, stream>>>(X, ewt, edge_b, edges, score_W, out, 2047, 3); // node-levels 13..11
    sub_kernel<<<128, 256, 0, stream>>>(X, ewt, edge_b, edges, score_W, out, 127, 4);   // node-levels 10..7
    sub_kernel<<<8, 256, 0, stream>>>(X, ewt, edge_b, edges, score_W, out, 7, 4);       // node-levels 6..3
    sub_kernel<<<1, 256, 0, stream>>>(X, ewt, edge_b, edges, score_W, out, 0, 3);       // node-levels 2..0 + root
}

// Round 10
// 332.252 us; speedup vs baseline: 1.1122x; 1.1122x over previous
//
#include <hip/hip_runtime.h>

#define D 128
#define NLVL 17          // parent levels 0..16
#define TS 128           // rows per big GEMM tile
#define LVLPAD 1024      // per-level perm slack for group padding
#define LDSTR 136        // LDS row stride in bf16 elems (272B: conflict-free b128)
#define LEAF_BLKS 1032   // ceil((131072 + 8*127)/128)
#define CHUNK 2048
#define CNT_BLKS 128

typedef float  floatx4 __attribute__((ext_vector_type(4)));
typedef short  shortx8 __attribute__((ext_vector_type(8)));

__device__ __forceinline__ unsigned short f2bf(float f) {   // RNE fp32->bf16
    unsigned u = __float_as_uint(f);
    u += 0x7FFFu + ((u >> 16) & 1u);
    return (unsigned short)(u >> 16);
}
__device__ __forceinline__ float bf2f(unsigned short h) {
    return __uint_as_float(((unsigned)h) << 16);
}
__device__ __forceinline__ int lvl_base_dev(int l) { return ((2 << l) - 2) + LVLPAD * l; }

// ============ prep (fused): compose->cwt+dcomp | ewt/dwt transpose | sv/s0+ctr0 | count | vec2bf ============
__global__ __launch_bounds__(256) void prep_kernel(
    const float* __restrict__ dW, const float* __restrict__ db,
    const float* __restrict__ eW, const float* __restrict__ eb,
    const float* __restrict__ sWs, const float* __restrict__ vecs,
    const int* __restrict__ edges,
    unsigned short* __restrict__ ewt, unsigned short* __restrict__ cwt,
    unsigned short* __restrict__ dwt, float* __restrict__ dcomp,
    float* __restrict__ sv, float* __restrict__ s0, int* __restrict__ ctr,
    int* __restrict__ gcnt128, int Nn,
    unsigned short* __restrict__ vbf, int n4)
{
    __shared__ float smem[8448];
    const int b = blockIdx.x, t = threadIdx.x;
    if (b < 32) {
        // ---- compose: C_e[:, cc*32..] = dW @ eW_e -> cwt (bf16 [n][k]) + dcomp ----
        float* w_s = smem;          // [k][32] slice of eW_e
        float* cs  = smem + 4096;   // [k][33] C block (padded)
        const int e = b >> 2, cc = b & 3;
        for (int i = t; i < D * 8; i += 256) {
            const int k = i >> 3, j4 = i & 7;
            ((float4*)w_s)[i] = ((const float4*)eW)[((size_t)e * D + k) * 32 + cc * 8 + j4];
        }
        __syncthreads();
        const int r2 = t >> 1, h = t & 1;
        float4 acc[4];
        #pragma unroll
        for (int m = 0; m < 4; m++) acc[m] = make_float4(0.f, 0.f, 0.f, 0.f);
        for (int k = 0; k < D; k++) {
            const float a = dW[(size_t)r2 * D + k];
            #pragma unroll
            for (int m = 0; m < 4; m++) {
                const float4 w4 = ((const float4*)w_s)[k * 8 + h * 4 + m];
                acc[m].x += a * w4.x; acc[m].y += a * w4.y; acc[m].z += a * w4.z; acc[m].w += a * w4.w;
            }
        }
        #pragma unroll
        for (int m = 0; m < 4; m++) {
            cs[r2 * 33 + h * 16 + m * 4 + 0] = acc[m].x;
            cs[r2 * 33 + h * 16 + m * 4 + 1] = acc[m].y;
            cs[r2 * 33 + h * 16 + m * 4 + 2] = acc[m].z;
            cs[r2 * 33 + h * 16 + m * 4 + 3] = acc[m].w;
        }
        __syncthreads();
        {
            const int nn = t >> 3, kseg = t & 7, k0 = kseg * 16;
            unsigned ow[8];
            #pragma unroll
            for (int i2 = 0; i2 < 8; i2++) {
                const unsigned short lo = f2bf(cs[(k0 + 2 * i2) * 33 + nn]);
                const unsigned short hi = f2bf(cs[(k0 + 2 * i2 + 1) * 33 + nn]);
                ow[i2] = (unsigned)lo | ((unsigned)hi << 16);
            }
            uint4* dstp = (uint4*)(cwt + (size_t)e * D * D + (size_t)(cc * 32 + nn) * D + k0);
            dstp[0] = make_uint4(ow[0], ow[1], ow[2], ow[3]);
            dstp[1] = make_uint4(ow[4], ow[5], ow[6], ow[7]);
        }
        if (t < 32) {
            float a2 = 0.f;
            for (int k = 0; k < D; k++) a2 += db[k] * w_s[k * 32 + t];
            dcomp[e * D + cc * 32 + t] = a2 + eb[e * D + cc * 32 + t];
        }
    } else if (b < 41) {
        // ---- transpose to bf16 [n][k]: b-32<8 -> ewt[e], b==40 -> dwt ----
        float* lds = smem;   // 64 x 129
        const int bb = b - 32;
        const float* src = (bb < 8) ? (eW + (size_t)bb * D * D) : dW;
        unsigned short* dst = (bb < 8) ? (ewt + (size_t)bb * D * D) : dwt;
        for (int half = 0; half < 2; half++) {
            __syncthreads();
            for (int i = t; i < 64 * D / 4; i += 256) {
                float4 v = ((const float4*)src)[half * (64 * D / 4) + i];
                const int k = (i * 4) >> 7, n = (i * 4) & 127;
                lds[k * 129 + n]     = v.x;
                lds[k * 129 + n + 1] = v.y;
                lds[k * 129 + n + 2] = v.z;
                lds[k * 129 + n + 3] = v.w;
            }
            __syncthreads();
            const int n = t >> 1, hh = t & 1;
            for (int kk = 0; kk < 32; kk++) {
                const int k = hh * 32 + kk;
                dst[(size_t)n * D + half * 64 + k] = f2bf(lds[k * 129 + n]);
            }
        }
    } else if (b == 41) {
        // ---- sv = data_W @ score_W, s0 = data_b . score_W; zero ctr ----
        float* red = smem;
        if (t < 32) ctr[t] = 0;
        if (t < D) {
            float acc = 0.f;
            for (int j = 0; j < D; j++) acc += dW[(size_t)t * D + j] * sWs[j];
            sv[t] = acc;
        }
        red[t] = (t < D) ? db[t] * sWs[t] : 0.f;
        __syncthreads();
        for (int s = 128; s > 0; s >>= 1) { if (t < s) red[t] += red[t + s]; __syncthreads(); }
        if (t == 0) s0[0] = red[0];
    } else if (b < 42 + CNT_BLKS) {
        // ---- counts for parent-levels 13..16 (children c >= 16383) ----
        int* lc = (int*)smem;
        if (t < 32) lc[t] = 0;
        __syncthreads();
        for (int c = 16383 + (b - 42) * 256 + t; c < Nn; c += CNT_BLKS * 256) {
            const int e = edges[c];
            const int p = (c - 1) >> 1;
            const int l = 31 - __clz(p + 1);      // 13..16
            atomicAdd(&lc[(l - 13) * 8 + e], 1);
        }
        __syncthreads();
        if (t < 32) gcnt128[(b - 42) * 32 + t] = lc[t];
    } else {
        // ---- vec2bf grid-stride ----
        for (int i = (b - 42 - CNT_BLKS) * 256 + t; i < n4; i += (gridDim.x - 42 - CNT_BLKS) * 256) {
            const float4 v = ((const float4*)vecs)[i];
            uint2 o;
            o.x = (unsigned)f2bf(v.x) | ((unsigned)f2bf(v.y) << 16);
            o.y = (unsigned)f2bf(v.z) | ((unsigned)f2bf(v.w) << 16);
            ((uint2*)vbf)[i] = o;
        }
    }
}

// ============ place (+local prefix): levels 13..16; block 0 publishes gstart/glim ============
__global__ __launch_bounds__(256) void place_kernel(
    const int* __restrict__ edges, const int* __restrict__ gcnt128,
    int* __restrict__ gstart, int* __restrict__ glim,
    int* __restrict__ ctr, int* __restrict__ perm, int Nn)
{
    __shared__ unsigned char key_s[CHUNK];
    __shared__ int part[256];
    __shared__ int tot[32];
    __shared__ int lcnt[32], lbase[32];
    __shared__ int gs_s[4 * 9], gl_s[32];
    const int t = threadIdx.x;
    {   // redundant per-block reduction of gcnt128 -> tot[32]
        const int k = t & 31, bs = t >> 5;
        int s = 0;
        for (int bb = bs; bb < CNT_BLKS; bb += 8) s += gcnt128[bb * 32 + k];
        part[t] = s;
    }
    if (t < 32) lcnt[t] = 0;
    __syncthreads();
    if (t < 32) {
        int tt = 0;
        #pragma unroll
        for (int i = 0; i < 8; i++) tt += part[t + 32 * i];
        tot[t] = tt;
    }
    __syncthreads();
    if (t == 0) {
        for (int li = 0; li < 4; li++) {
            int acc = 0;
            for (int e = 0; e < 8; e++) {
                gs_s[li * 9 + e] = acc;
                gl_s[li * 8 + e] = acc + tot[li * 8 + e];
                acc = (acc + tot[li * 8 + e] + (TS - 1)) & ~(TS - 1);
            }
            gs_s[li * 9 + 8] = acc;
        }
    }
    __syncthreads();
    if (blockIdx.x == 0 && t < 36) {
        gstart[13 * 9 + t] = gs_s[t];
        if (t < 32) glim[13 * 8 + t] = gl_s[t];
    }
    const int base = 16383 + blockIdx.x * CHUNK;
    for (int i = t; i < CHUNK; i += 256) {
        const int c = base + i;
        if (c < Nn) {
            const int e = edges[c];
            const int p = (c - 1) >> 1;
            const int l = 31 - __clz(p + 1);
            const int kk = (l - 13) * 8 + e;
            key_s[i] = (unsigned char)kk;
            atomicAdd(&lcnt[kk], 1);
        } else key_s[i] = 255;
    }
    __syncthreads();
    if (t < 32) {
        const int n = lcnt[t];
        lbase[t] = n ? atomicAdd(&ctr[t], n) : 0;
        lcnt[t] = 0;
    }
    __syncthreads();
    for (int i = t; i < CHUNK; i += 256) {
        const int c = base + i;
        if (c >= Nn) continue;
        const int kk = key_s[i];
        if (kk == 255) continue;
        const int off = atomicAdd(&lcnt[kk], 1);
        const int l = (kk >> 3) + 13, e = kk & 7;
        const int pos = gs_s[(l - 13) * 9 + e] + lbase[kk] + off;
        perm[lvl_base_dev(l) + pos] = c;
    }
}

// ============ merged leaf GEMM + embed (STAGED version — measured 56.9 us) ============
__global__ __launch_bounds__(256, 4) void leaf_embed_kernel(
    unsigned short* __restrict__ X,
    const unsigned short* __restrict__ vbf,
    const int* __restrict__ data,
    const int* __restrict__ perm,
    const int* __restrict__ gstart9,
    const int* __restrict__ glim8,
    const unsigned short* __restrict__ cwt,
    const float* __restrict__ dcomp,
    const float* __restrict__ sv, const float* __restrict__ s0p,
    const unsigned short* __restrict__ dwt,
    const float* __restrict__ db,
    float* __restrict__ out,
    int NI, int lbase_leaf)
{
    __shared__ unsigned short a_s[TS * LDSTR];   // ~34.8 KB
    const int t = threadIdx.x;
    const bool is_leaf = (blockIdx.x < LEAF_BLKS);
    const int r = t >> 1, h = t & 1;

    int e = 0, c;
    const unsigned short* Wg;
    const float* bias;
    if (is_leaf) {
        const int ts = blockIdx.x * TS;
        if (ts >= gstart9[8]) return;
        #pragma unroll
        for (int j = 1; j < 8; j++) if (ts >= gstart9[j]) e = j;
        const int p = ts + r;
        c = (p < glim8[e]) ? perm[lbase_leaf + p] : -1;
        Wg = cwt + (size_t)e * D * D;
        bias = dcomp + (size_t)e * D;
    } else {
        const int node = (blockIdx.x - LEAF_BLKS) * TS + r;
        c = (node < NI) ? node : -1;
        Wg = dwt;
        bias = db;
    }

    {   // stage A (bf16 gather) + fused leaf score
        unsigned short* dst = a_s + r * LDSTR + h * 64;
        if (c >= 0) {
            const uint4* src = (const uint4*)(vbf + (size_t)data[c] * D + h * 64);
            if (is_leaf) {
                float sc = 0.f;
                #pragma unroll
                for (int j = 0; j < 8; j++) {
                    const uint4 v = src[j];
                    const unsigned* pv = (const unsigned*)&v;
                    #pragma unroll
                    for (int u = 0; u < 4; u++) {
                        const int n = h * 64 + j * 8 + u * 2;
                        sc += bf2f((unsigned short)pv[u]) * sv[n]
                            + bf2f((unsigned short)(pv[u] >> 16)) * sv[n + 1];
                    }
                    ((uint4*)dst)[j] = v;
                }
                sc += __shfl_xor(sc, 1, 64);
                if (h == 0) out[c] = sc + s0p[0];
            } else {
                #pragma unroll
                for (int j = 0; j < 8; j++) ((uint4*)dst)[j] = src[j];
            }
        } else {
            #pragma unroll
            for (int j = 0; j < 8; j++) ((uint4*)dst)[j] = make_uint4(0u, 0u, 0u, 0u);
        }
    }
    __syncthreads();

    const int lane = t & 63, wv = t >> 6;
    const int cq = lane & 15, q = lane >> 4;
    const floatx4 z4 = {0.f, 0.f, 0.f, 0.f};
    floatx4 acc[8][2];
    #pragma unroll
    for (int i = 0; i < 8; i++) { acc[i][0] = z4; acc[i][1] = z4; }
    #pragma unroll
    for (int ks = 0; ks < 4; ks++) {
        shortx8 bfr[2];
        #pragma unroll
        for (int nl = 0; nl < 2; nl++) {
            const int n = (wv * 2 + nl) * 16 + cq;
            bfr[nl] = *(const shortx8*)(Wg + (size_t)n * D + ks * 32 + q * 8);
        }
        #pragma unroll
        for (int mt = 0; mt < 8; mt++) {
            const shortx8 af = *(const shortx8*)(a_s + (mt * 16 + cq) * LDSTR + ks * 32 + q * 8);
            acc[mt][0] = __builtin_amdgcn_mfma_f32_16x16x32_bf16(af, bfr[0], acc[mt][0], 0, 0, 0);
            acc[mt][1] = __builtin_amdgcn_mfma_f32_16x16x32_bf16(af, bfr[1], acc[mt][1], 0, 0, 0);
        }
    }
    __syncthreads();
    #pragma unroll
    for (int nl = 0; nl < 2; nl++) {
        const int n = (wv * 2 + nl) * 16 + cq;
        const float bn = bias[n];
        #pragma unroll
        for (int mt = 0; mt < 8; mt++) {
            #pragma unroll
            for (int rg = 0; rg < 4; rg++) {
                const int m = mt * 16 + q * 4 + rg;
                a_s[m * LDSTR + n] = f2bf(acc[mt][nl][rg] + bn);
            }
        }
    }
    __syncthreads();
    if (c >= 0) {
        uint4* dst = (uint4*)(X + (size_t)c * D + h * 64);
        const uint4* srcl = (const uint4*)(a_s + r * LDSTR + h * 64);
        #pragma unroll
        for (int j = 0; j < 8; j++) dst[j] = srcl[j];
    }
}

// ============ big tree GEMM (parent-levels 15..13): combine+score+ReLU staged, W direct ============
__global__ __launch_bounds__(256, 4) void tree_gemm_kernel(
    unsigned short* __restrict__ X,
    const int* __restrict__ perm,
    const int* __restrict__ gstart9,
    const int* __restrict__ glim8,
    const unsigned short* __restrict__ ewt,
    const float* __restrict__ eb,
    const float* __restrict__ svec,
    float* __restrict__ out,
    int lbase)
{
    __shared__ unsigned short a_s[TS * LDSTR];
    const int t = threadIdx.x;
    const int ts = blockIdx.x * TS;
    if (ts >= gstart9[8]) return;
    int e = 0;
    #pragma unroll
    for (int j = 1; j < 8; j++) if (ts >= gstart9[j]) e = j;
    const int r = t >> 1, h = t & 1;
    const int p = ts + r;
    const int c = (p < glim8[e]) ? perm[lbase + p] : -1;
    const unsigned short* Wg = ewt + (size_t)e * D * D;

    {   // stage A: fused combine + score + ReLU
        unsigned short* dst = a_s + r * LDSTR + h * 64;
        if (c >= 0) {
            const uint4* xr = (const uint4*)(X + (size_t)c * D + h * 64);
            const uint4* ya = (const uint4*)(X + (size_t)(2 * c + 1) * D + h * 64);
            const uint4* yb = (const uint4*)(X + (size_t)(2 * c + 2) * D + h * 64);
            const float inv3 = 1.0f / 3.0f;
            float sc = 0.f;
            #pragma unroll
            for (int j = 0; j < 8; j++) {
                uint4 ra = xr[j], rb = ya[j], rc = yb[j];
                const unsigned* pa = (const unsigned*)&ra;
                const unsigned* pb = (const unsigned*)&rb;
                const unsigned* pc = (const unsigned*)&rc;
                unsigned ou[4];
                #pragma unroll
                for (int u = 0; u < 4; u++) {
                    const float h0 = (bf2f((unsigned short)pa[u]) + bf2f((unsigned short)pb[u])
                                    + bf2f((unsigned short)pc[u])) * inv3;
                    const float h1 = (bf2f((unsigned short)(pa[u] >> 16)) + bf2f((unsigned short)(pb[u] >> 16))
                                    + bf2f((unsigned short)(pc[u] >> 16))) * inv3;
                    const int n = h * 64 + j * 8 + u * 2;
                    sc += h0 * svec[n] + h1 * svec[n + 1];
                    unsigned short q0 = f2bf(h0), q1 = f2bf(h1);
                    q0 = (q0 & 0x8000u) ? 0 : q0;
                    q1 = (q1 & 0x8000u) ? 0 : q1;
                    ou[u] = (unsigned)q0 | ((unsigned)q1 << 16);
                }
                ((uint4*)dst)[j] = make_uint4(ou[0], ou[1], ou[2], ou[3]);
            }
            sc += __shfl_xor(sc, 1, 64);
            if (h == 0) out[c] = sc;
        } else {
            #pragma unroll
            for (int j = 0; j < 8; j++) ((uint4*)dst)[j] = make_uint4(0u, 0u, 0u, 0u);
        }
    }
    __syncthreads();
    const int lane = t & 63, wv = t >> 6;
    const int cq = lane & 15, q = lane >> 4;
    const floatx4 z4 = {0.f, 0.f, 0.f, 0.f};
    floatx4 acc[8][2];
    #pragma unroll
    for (int i = 0; i < 8; i++) { acc[i][0] = z4; acc[i][1] = z4; }
    #pragma unroll
    for (int ks = 0; ks < 4; ks++) {
        shortx8 bfr[2];
        #pragma unroll
        for (int nl = 0; nl < 2; nl++) {
            const int n = (wv * 2 + nl) * 16 + cq;
            bfr[nl] = *(const shortx8*)(Wg + (size_t)n * D + ks * 32 + q * 8);
        }
        #pragma unroll
        for (int mt = 0; mt < 8; mt++) {
            const shortx8 af = *(const shortx8*)(a_s + (mt * 16 + cq) * LDSTR + ks * 32 + q * 8);
            acc[mt][0] = __builtin_amdgcn_mfma_f32_16x16x32_bf16(af, bfr[0], acc[mt][0], 0, 0, 0);
            acc[mt][1] = __builtin_amdgcn_mfma_f32_16x16x32_bf16(af, bfr[1], acc[mt][1], 0, 0, 0);
        }
    }
    __syncthreads();
    #pragma unroll
    for (int nl = 0; nl < 2; nl++) {
        const int n = (wv * 2 + nl) * 16 + cq;
        const float bn = eb[(size_t)e * D + n];
        #pragma unroll
        for (int mt = 0; mt < 8; mt++) {
            #pragma unroll
            for (int rg = 0; rg < 4; rg++) {
                const int m = mt * 16 + q * 4 + rg;
                a_s[m * LDSTR + n] = f2bf(acc[mt][nl][rg] + bn);
            }
        }
    }
    __syncthreads();
    if (c >= 0) {
        uint4* dst = (uint4*)(X + (size_t)c * D + h * 64);
        const uint4* srcl = (const uint4*)(a_s + r * LDSTR + h * 64);
        #pragma unroll
        for (int j = 0; j < 8; j++) dst[j] = srcl[j];
    }
}

// ============ subtree kernel (top levels): fp32 W column loads, __syncthreads between depths ============
__global__ __launch_bounds__(256) void sub_kernel(
    unsigned short* __restrict__ X,
    const float* __restrict__ eW,     // original fp32 [8][128][128] (k-major)
    const float* __restrict__ eb,
    const int* __restrict__ edges,
    const float* __restrict__ sW,
    float* __restrict__ out,
    int rbase, int nlev)
{
    __shared__ __align__(16) float xbuf[4][D];
    const int t = threadIdx.x, wv = t >> 6, lane = t & 63;
    const int u = rbase + blockIdx.x;
    const int j2 = lane * 2;
    const float inv3 = 1.0f / 3.0f;

    for (int lev = nlev - 1; lev >= 0; lev--) {
        const int first = ((u + 1) << lev) - 1;
        const int cnt = 1 << lev;
        for (int i = wv; i < cnt; i += 4) {
            const int n = first + i;
            const unsigned ra = *(const unsigned*)(X + (size_t)n * D + j2);
            const unsigned rb = *(const unsigned*)(X + (size_t)(2 * n + 1) * D + j2);
            const unsigned rc = *(const unsigned*)(X + (size_t)(2 * n + 2) * D + j2);
            const float h0 = (bf2f((unsigned short)ra) + bf2f((unsigned short)rb)
                            + bf2f((unsigned short)rc)) * inv3;
            const float h1 = (bf2f((unsigned short)(ra >> 16)) + bf2f((unsigned short)(rb >> 16))
                            + bf2f((unsigned short)(rc >> 16))) * inv3;
            float sc = h0 * sW[j2] + h1 * sW[j2 + 1];
            #pragma unroll
            for (int o = 32; o > 0; o >>= 1) sc += __shfl_xor(sc, o, 64);
            if (lane == 0) out[n] = sc;
            if (n == 0) continue;
            float2 x2 = make_float2(fmaxf(h0, 0.f), fmaxf(h1, 0.f));
            *(float2*)(xbuf[wv] + j2) = x2;
            const int e = edges[n];
            const float* W = eW + (size_t)e * D * D;
            float y0 = 0.f, y1 = 0.f;
            #pragma unroll 8
            for (int k4 = 0; k4 < 32; k4++) {
                const float4 xk = *(const float4*)(xbuf[wv] + k4 * 4);
                const float2 w0 = *(const float2*)(W + (size_t)(k4 * 4 + 0) * D + j2);
                const float2 w1 = *(const float2*)(W + (size_t)(k4 * 4 + 1) * D + j2);
                const float2 w2 = *(const float2*)(W + (size_t)(k4 * 4 + 2) * D + j2);
                const float2 w3 = *(const float2*)(W + (size_t)(k4 * 4 + 3) * D + j2);
                y0 += xk.x * w0.x + xk.y * w1.x + xk.z * w2.x + xk.w * w3.x;
                y1 += xk.x * w0.y + xk.y * w1.y + xk.z * w2.y + xk.w * w3.y;
            }
            y0 += eb[e * D + j2];
            y1 += eb[e * D + j2 + 1];
            const unsigned o = (unsigned)f2bf(y0) | ((unsigned)f2bf(y1) << 16);
            *(unsigned*)(X + (size_t)n * D + j2) = o;
        }
        __syncthreads();
    }
}

extern "C" void kernel_launch(void* const* d_in, const int* in_sizes, int n_in,
                              void* d_out, int out_size, void* d_ws, size_t ws_size,
                              hipStream_t stream) {
    const int*   data      = (const int*)d_in[0];
    const int*   edges     = (const int*)d_in[1];
    const float* data_vecs = (const float*)d_in[2];
    const float* data_W    = (const float*)d_in[3];
    const float* data_b    = (const float*)d_in[4];
    const float* edge_W    = (const float*)d_in[5];
    const float* edge_b    = (const float*)d_in[6];
    const float* score_W   = (const float*)d_in[7];
    float* out = (float*)d_out;

    const int Nn = in_sizes[0];          // 2^18 - 1
    const int NI = Nn >> 1;              // internal nodes: 2^17 - 1
    const int VD = in_sizes[2];          // V * D
    const int PERM_TOTAL = (Nn - 1) + LVLPAD * NLVL;

    char* w = (char*)d_ws;
    size_t off = 0;
    unsigned short* X = (unsigned short*)(w + off); off += (size_t)Nn * D * 2;
    int* perm = (int*)(w + off);  off += (size_t)PERM_TOTAL * 4;
    off = (off + 255) & ~(size_t)255;
    int* gstart  = (int*)(w + off); off += NLVL * 9 * 4;
    int* glim    = (int*)(w + off); off += NLVL * 8 * 4;
    int* gcnt128 = (int*)(w + off); off += CNT_BLKS * 32 * 4;
    int* ctr     = (int*)(w + off); off += 32 * 4;
    off = (off + 255) & ~(size_t)255;
    float* dcomp = (float*)(w + off); off += 8 * D * 4;
    float* sv    = (float*)(w + off); off += D * 4;
    float* s0    = (float*)(w + off); off += 256;
    off = (off + 255) & ~(size_t)255;
    unsigned short* ewt = (unsigned short*)(w + off); off += (size_t)8 * D * D * 2;
    unsigned short* cwt = (unsigned short*)(w + off); off += (size_t)8 * D * D * 2;
    unsigned short* dwt = (unsigned short*)(w + off); off += (size_t)D * D * 2;
    off = (off + 255) & ~(size_t)255;
    unsigned short* vbf = (unsigned short*)(w + off); off += (size_t)VD * 2;

    // 1: fused prep (weights, sv/s0, ctr zero, counts, vec2bf)
    prep_kernel<<<42 + CNT_BLKS + 1024, 256, 0, stream>>>(
        data_W, data_b, edge_W, edge_b, score_W, data_vecs, edges,
        ewt, cwt, dwt, dcomp, sv, s0, ctr, gcnt128, Nn, vbf, VD / 4);

    // 2: place (+redundant local prefix; block 0 publishes gstart/glim)
    const int place_blks = (Nn - 16383 + CHUNK - 1) / CHUNK;
    place_kernel<<<place_blks, 256, 0, stream>>>(edges, gcnt128, gstart, glim, ctr, perm, Nn);

    // 3: merged leaf GEMM (node-level 17) + embed (internal raw), staged
    {
        const int embed_blks = (NI + TS - 1) / TS;
        const int lbase_leaf = ((2 << 16) - 2) + LVLPAD * 16;
        leaf_embed_kernel<<<LEAF_BLKS + embed_blks, 256, 0, stream>>>(
            X, vbf, data, perm, gstart + 16 * 9, glim + 16 * 8,
            cwt, dcomp, sv, s0, dwt, data_b, out, NI, lbase_leaf);
    }

    // 4..6: big internal parent-levels 15..13 (node-levels 16..14)
    for (int l = 15; l >= 13; l--) {
        const int M = 2 << l;
        const int lbase = ((2 << l) - 2) + LVLPAD * l;
        tree_gemm_kernel<<<M / TS + 8, 256, 0, stream>>>(
            X, perm, gstart + l * 9, glim + l * 8, ewt, edge_b, score_W, out, lbase);
    }

    // 7..10: top of tree via subtree-owned blocks (fp32 W)
    sub_kernel<<<2048, 256, 0, stream>>>(X, edge_W, edge_b, edges, score_W, out, 2047, 3); // node-levels 13..11
    sub_kernel<<<128, 256, 0, stream>>>(X, edge_W, edge_b, edges, score_W, out, 127, 4);   // node-levels 10..7
    sub_kernel<<<8, 256, 0, stream>>>(X, edge_W, edge_b, edges, score_W, out, 7, 4);       // node-levels 6..3
    sub_kernel<<<1, 256, 0, stream>>>(X, edge_W, edge_b, edges, score_W, out, 0, 3);       // node-levels 2..0 + root
}